// Round 16
// baseline (1557.143 us; speedup 1.0000x reference)
//
#include <hip/hip_runtime.h>
#include <hip/hip_bf16.h>
#include <cmath>
#include <cstdint>

// ---------------------------------------------------------------------------
// Stacked 2-layer Elman RNN, bf16 hi/lo-split MFMA (3-pass) everywhere.
//   fused split_all + gather_split -> bf16 hi/lo
//   A0 = embsplit @ Wx0^T + bh0                         (MFMA GEMM)
//   ONE persistent cooperative kernel (256 blocks):
//     blocks 0-63   (layer 0): h0[t] = tanh(A0[t] + h0[t-1] @ Wh0^T)
//     blocks 64-127 (layer 1): h1[t] = tanh(h0[t]@Wx1^T + h1[t-1]@Wh1^T + bh1)
//     blocks 128-255 (logits workers): wait flags1[t_hi] then compute
//       logits 128x128 tile; A-panel (H1) read via AGENT-scope relaxed u64
//       atomic loads (sc0sc1 -> LLC-direct; immune to stale L2 lines from
//       speculative prefetch -- the R10/R11 failure mechanism).
//   R9 bug fixed: flags now in the dead Wx0l ws region (workers write d_out!),
//   memset stream-ordered after the A0 GEMM.
//   Layer-1 publish: plain write-through stores + one agent RELEASE fence
//   before the flag fetch_add (ns-scale consumers).  Layer-0: R12-exact.
//   h_final = hi+lo of t=69 (after the persist).
// ---------------------------------------------------------------------------

using u16 = unsigned short;
using u32 = unsigned int;
using u64 = unsigned long long;
typedef __attribute__((ext_vector_type(8))) short short8;  // bf16x8 MFMA frag
typedef __attribute__((ext_vector_type(4))) float f32x4;

#define MFMA_BF16(a, b, c) __builtin_amdgcn_mfma_f32_16x16x32_bf16((a), (b), (c), 0, 0, 0)

__device__ __forceinline__ u16 bf16_rne(float x) {
    u32 u = __float_as_uint(x);
    u32 r = u + 0x7FFFu + ((u >> 16) & 1u);
    return (u16)(r >> 16);
}
__device__ __forceinline__ float bf16_f(u16 h) {
    return __uint_as_float(((u32)h) << 16);
}
__device__ __forceinline__ void split2(float x, u16& hi, u16& lo) {
    hi = bf16_rne(x);
    lo = bf16_rne(x - bf16_f(hi));
}
__device__ __forceinline__ u64 pack4(u16 a, u16 b, u16 c, u16 d) {
    return (u64)a | ((u64)b << 16) | ((u64)c << 32) | ((u64)d << 48);
}

// ---- cross-workgroup sync --------------------------------------------------
__device__ __forceinline__ void wait_count(int* f, int target) {
    if (threadIdx.x == 0) {
        while (__hip_atomic_load(f, __ATOMIC_RELAXED, __HIP_MEMORY_SCOPE_AGENT) < target)
            __builtin_amdgcn_s_sleep(1);
    }
    __syncthreads();
}
// R12-exact publish (layer 0: consumers are us-late, 8 green rounds).
__device__ __forceinline__ void signal_done(int* f) {
    __syncthreads();   // vmcnt(0): write-through h-stores drained
    if (threadIdx.x == 0)
        __hip_atomic_fetch_add(f, 1, __ATOMIC_RELAXED, __HIP_MEMORY_SCOPE_AGENT);
}
// Layer-1 publish: release fence orders h-stores ahead of the flag at the
// coherence point (workers consume within ~ns of the flag flip).
__device__ __forceinline__ void signal_done_rel(int* f) {
    __syncthreads();
    if (threadIdx.x == 0) {
        __builtin_amdgcn_fence(__ATOMIC_RELEASE, "agent");
        __hip_atomic_fetch_add(f, 1, __ATOMIC_RELAXED, __HIP_MEMORY_SCOPE_AGENT);
    }
}

// ---------------- fused split: weights + hidden -> bf16 hi/lo --------------
__global__ __launch_bounds__(256) void split_all_kernel(
    const float* __restrict__ Wx0, u16* Wx0h, u16* Wx0l,
    const float* __restrict__ Wx1, u16* Wx1h, u16* Wx1l,
    const float* __restrict__ Wh0, u16* Wh0h, u16* Wh0l,
    const float* __restrict__ Wh1, u16* Wh1h, u16* Wh1l,
    const float* __restrict__ Wy,  u16* Wyh,  u16* Wyl,
    const float* __restrict__ hid, u16* hsh,  u16* hsl)
{
    const int n0 = 131072;    // Wx0: 1024*512/4
    const int n1 = 262144;    // Wx1
    const int n2 = 262144;    // Wh0
    const int n3 = 262144;    // Wh1
    const int n4s = 2560000;  // Wy
    const int n5 = 32768;     // hidden (both layers; zeros -> benign layout)
    int g = blockIdx.x * 256 + threadIdx.x;
    const float* src; u16* hi; u16* lo; int off;
    if      (g < n0)                       { src=Wx0; hi=Wx0h; lo=Wx0l; off=g; }
    else if ((g -= n0) < n1)               { src=Wx1; hi=Wx1h; lo=Wx1l; off=g; }
    else if ((g -= n1) < n2)               { src=Wh0; hi=Wh0h; lo=Wh0l; off=g; }
    else if ((g -= n2) < n3)               { src=Wh1; hi=Wh1h; lo=Wh1l; off=g; }
    else if ((g -= n3) < n4s)              { src=Wy;  hi=Wyh;  lo=Wyl;  off=g; }
    else if ((g -= n4s) < n5)              { src=hid; hi=hsh;  lo=hsl;  off=g; }
    else return;
    float4 v = *reinterpret_cast<const float4*>(src + (size_t)off * 4);
    u16 h0,h1,h2,h3,l0,l1,l2,l3;
    split2(v.x,h0,l0); split2(v.y,h1,l1); split2(v.z,h2,l2); split2(v.w,h3,l3);
    ushort4 H = {h0,h1,h2,h3}, L = {l0,l1,l2,l3};
    *reinterpret_cast<ushort4*>(hi + (size_t)off * 4) = H;
    *reinterpret_cast<ushort4*>(lo + (size_t)off * 4) = L;
}

// ---------------- fused gather(emb, idx) + split:  out [M][512] -------------
__global__ __launch_bounds__(256) void gather_split_kernel(
    const float* __restrict__ emb, const int* __restrict__ idx,
    u16* __restrict__ hi, u16* __restrict__ lo, int n4)
{
    int g = blockIdx.x * 256 + threadIdx.x;
    if (g >= n4) return;
    int m  = g >> 7;
    int c4 = g & 127;
    const float* src = emb + (size_t)idx[m] * 512 + c4 * 4;
    float4 v = *reinterpret_cast<const float4*>(src);
    u16 h0,h1,h2,h3,l0,l1,l2,l3;
    split2(v.x,h0,l0); split2(v.y,h1,l1); split2(v.z,h2,l2); split2(v.w,h3,l3);
    ushort4 H = {h0,h1,h2,h3}, L = {l0,l1,l2,l3};
    size_t o = (size_t)m * 512 + c4 * 4;
    *reinterpret_cast<ushort4*>(hi + o) = H;
    *reinterpret_cast<ushort4*>(lo + o) = L;
}

// ---------------- bf16-split MFMA GEMM tile body (device) ------------------
__device__ __forceinline__ void gemm_tile(
    const u16* __restrict__ Ah, const u16* __restrict__ Al,
    const u16* __restrict__ Bh, const u16* __restrict__ Bl,
    const float* __restrict__ bias, float* __restrict__ C,
    int N, int K, int m0, int n0,
    u16* sAh, u16* sAl, u16* sBh, u16* sBl)
{
    const int tid  = threadIdx.x;
    const int lane = tid & 63;
    const int w    = tid >> 6;
    const int wr   = w >> 1, wc = w & 1;

    f32x4 acc[4][4];
    #pragma unroll
    for (int i = 0; i < 4; ++i)
        #pragma unroll
        for (int j = 0; j < 4; ++j) acc[i][j] = 0.0f;

    for (int k0 = 0; k0 < K; k0 += 32) {
        #pragma unroll
        for (int r = 0; r < 2; ++r) {
            int s   = r * 256 + tid;
            int row = s >> 2, q = s & 3;
            int gq  = q ^ (row & 3);
            int l16 = row * 32 + q * 8;
            size_t ga = (size_t)(m0 + row) * K + k0 + gq * 8;
            int brow = n0 + row; if (brow >= N) brow = N - 1;
            size_t gb = (size_t)brow * K + k0 + gq * 8;
            *reinterpret_cast<int4*>(sAh + l16) = *reinterpret_cast<const int4*>(Ah + ga);
            *reinterpret_cast<int4*>(sAl + l16) = *reinterpret_cast<const int4*>(Al + ga);
            *reinterpret_cast<int4*>(sBh + l16) = *reinterpret_cast<const int4*>(Bh + gb);
            *reinterpret_cast<int4*>(sBl + l16) = *reinterpret_cast<const int4*>(Bl + gb);
        }
        __syncthreads();

        const int q4 = lane >> 4;
        short8 afh[4], afl[4];
        #pragma unroll
        for (int i = 0; i < 4; ++i) {
            int ra  = wr * 64 + i * 16 + (lane & 15);
            int off = ra * 32 + (q4 ^ (ra & 3)) * 8;
            afh[i] = *reinterpret_cast<const short8*>(sAh + off);
            afl[i] = *reinterpret_cast<const short8*>(sAl + off);
        }
        #pragma unroll
        for (int j = 0; j < 4; ++j) {
            int rb  = wc * 64 + j * 16 + (lane & 15);
            int off = rb * 32 + (q4 ^ (rb & 3)) * 8;
            short8 bfh = *reinterpret_cast<const short8*>(sBh + off);
            short8 bfl = *reinterpret_cast<const short8*>(sBl + off);
            #pragma unroll
            for (int i = 0; i < 4; ++i) {
                acc[i][j] = MFMA_BF16(afh[i], bfh, acc[i][j]);
                acc[i][j] = MFMA_BF16(afh[i], bfl, acc[i][j]);
                acc[i][j] = MFMA_BF16(afl[i], bfh, acc[i][j]);
            }
        }
        __syncthreads();
    }

    #pragma unroll
    for (int j = 0; j < 4; ++j) {
        int n = n0 + wc * 64 + j * 16 + (lane & 15);
        if (n < N) {
            float bv = bias[n];
            #pragma unroll
            for (int i = 0; i < 4; ++i) {
                #pragma unroll
                for (int r = 0; r < 4; ++r) {
                    int m = m0 + wr * 64 + i * 16 + (lane >> 4) * 4 + r;
                    C[(size_t)m * N + n] = acc[i][j][r] + bv;
                }
            }
        }
    }
}

// Worker variant: A-panel staged via AGENT-scope relaxed u64 atomic loads
// (sc0sc1 -> LLC-direct; no L1/L2 involvement -> no stale-line hazard).
__device__ __forceinline__ void gemm_tile_llcA(
    const u16* __restrict__ Ah, const u16* __restrict__ Al,
    const u16* __restrict__ Bh, const u16* __restrict__ Bl,
    const float* __restrict__ bias, float* __restrict__ C,
    int N, int K, int m0, int n0,
    u16* sAh, u16* sAl, u16* sBh, u16* sBl)
{
    const int tid  = threadIdx.x;
    const int lane = tid & 63;
    const int w    = tid >> 6;
    const int wr   = w >> 1, wc = w & 1;

    f32x4 acc[4][4];
    #pragma unroll
    for (int i = 0; i < 4; ++i)
        #pragma unroll
        for (int j = 0; j < 4; ++j) acc[i][j] = 0.0f;

    for (int k0 = 0; k0 < K; k0 += 32) {
        // A: 128 rows x 4 quads x 2 u64-halves = 1024 u64 per array; 4 rounds
        #pragma unroll
        for (int rr = 0; rr < 4; ++rr) {
            int u2  = rr * 256 + tid;
            int row = u2 >> 3, j = u2 & 7, q = j >> 1, hf = j & 1;
            int gq  = q ^ (row & 3);
            size_t ga = (size_t)(m0 + row) * K + k0 + gq * 8 + hf * 4;
            u64 vh = __hip_atomic_load((const u64*)(Ah + ga),
                                       __ATOMIC_RELAXED, __HIP_MEMORY_SCOPE_AGENT);
            u64 vl = __hip_atomic_load((const u64*)(Al + ga),
                                       __ATOMIC_RELAXED, __HIP_MEMORY_SCOPE_AGENT);
            int l16 = row * 32 + q * 8 + hf * 4;
            *reinterpret_cast<u64*>(sAh + l16) = vh;
            *reinterpret_cast<u64*>(sAl + l16) = vl;
        }
        // B (Wy): normal int4 staging
        #pragma unroll
        for (int r = 0; r < 2; ++r) {
            int s   = r * 256 + tid;
            int row = s >> 2, q = s & 3;
            int gq  = q ^ (row & 3);
            int brow = n0 + row; if (brow >= N) brow = N - 1;
            size_t gb = (size_t)brow * K + k0 + gq * 8;
            *reinterpret_cast<int4*>(sBh + row * 32 + q * 8) =
                *reinterpret_cast<const int4*>(Bh + gb);
            *reinterpret_cast<int4*>(sBl + row * 32 + q * 8) =
                *reinterpret_cast<const int4*>(Bl + gb);
        }
        __syncthreads();

        const int q4 = lane >> 4;
        short8 afh[4], afl[4];
        #pragma unroll
        for (int i = 0; i < 4; ++i) {
            int ra  = wr * 64 + i * 16 + (lane & 15);
            int off = ra * 32 + (q4 ^ (ra & 3)) * 8;
            afh[i] = *reinterpret_cast<const short8*>(sAh + off);
            afl[i] = *reinterpret_cast<const short8*>(sAl + off);
        }
        #pragma unroll
        for (int j = 0; j < 4; ++j) {
            int rb  = wc * 64 + j * 16 + (lane & 15);
            int off = rb * 32 + (q4 ^ (rb & 3)) * 8;
            short8 bfh = *reinterpret_cast<const short8*>(sBh + off);
            short8 bfl = *reinterpret_cast<const short8*>(sBl + off);
            #pragma unroll
            for (int i = 0; i < 4; ++i) {
                acc[i][j] = MFMA_BF16(afh[i], bfh, acc[i][j]);
                acc[i][j] = MFMA_BF16(afh[i], bfl, acc[i][j]);
                acc[i][j] = MFMA_BF16(afl[i], bfh, acc[i][j]);
            }
        }
        __syncthreads();
    }

    #pragma unroll
    for (int j = 0; j < 4; ++j) {
        int n = n0 + wc * 64 + j * 16 + (lane & 15);
        if (n < N) {
            float bv = bias[n];
            #pragma unroll
            for (int i = 0; i < 4; ++i) {
                #pragma unroll
                for (int r = 0; r < 4; ++r) {
                    int m = m0 + wr * 64 + i * 16 + (lane >> 4) * 4 + r;
                    C[(size_t)m * N + n] = acc[i][j][r] + bv;
                }
            }
        }
    }
}

// ---------------- standalone GEMM (A0 prologue) ----------------------------
__global__ __launch_bounds__(256) void gemm_mfma(
    const u16* __restrict__ Ah, const u16* __restrict__ Al,
    const u16* __restrict__ Bh, const u16* __restrict__ Bl,
    const float* __restrict__ bias, float* __restrict__ C,
    int M, int N, int K)
{
    __shared__ u16 sAh[128*32], sAl[128*32], sBh[128*32], sBl[128*32];
    gemm_tile(Ah, Al, Bh, Bl, bias, C, N, K,
              blockIdx.y * 128, blockIdx.x * 128, sAh, sAl, sBh, sBl);
}

// ---------------- persistent kernel: recurrence + logits workers -----------
// 256 blocks x 256 threads, cooperative, 1 block/CU.
// flags[0..69]  = # layer-0 blocks done with h0[t]
// flags[70..139]= # layer-1 blocks done with h1[t]
__global__ __launch_bounds__(256, 1) void rnn_persist5(
    const float* __restrict__ A0,
    const u16* __restrict__ hs0h, const u16* __restrict__ hs0l,
    const u16* __restrict__ hs1h, const u16* __restrict__ hs1l,
    u16* __restrict__ H0h, u16* __restrict__ H0l,
    u16* __restrict__ H1h, u16* __restrict__ H1l,
    const u16* __restrict__ Wh0h, const u16* __restrict__ Wh0l,
    const u16* __restrict__ Wx1h, const u16* __restrict__ Wx1l,
    const u16* __restrict__ Wh1h, const u16* __restrict__ Wh1l,
    const float* __restrict__ bh1, int* flags,
    const u16* __restrict__ Wyh, const u16* __restrict__ Wyl,
    const float* __restrict__ by, float* __restrict__ Cout)
{
    __shared__ u16 sW[65536];          // 128 KiB (weights / worker GEMM tiles)
    __shared__ float sStage[64 * 17];  // h-tile staging
    const int tid   = threadIdx.x;
    const int lane  = tid & 63;
    const int w     = tid >> 6;
    const size_t BH = 65536;

    if (blockIdx.x >= 128) {
        // ---------------- logits worker ----------------
        int wkr = (int)blockIdx.x - 128;
        u16* sAh = sW;
        u16* sAl = sW + 4096;
        u16* sBh = sW + 8192;
        u16* sBl = sW + 12288;
        const int NT = 35 * 79;                 // M/128=35, ceil(10000/128)=79
        for (int tile = wkr; tile < NT; tile += 128) {
            int mb = tile / 79, nb = tile % 79;
            int t_hi = 2 * mb + 1;              // last timestep in rows [mb*128, +128)
            wait_count(flags + 70 + t_hi, 64);
            gemm_tile_llcA(H1h, H1l, Wyh, Wyl, by, Cout, 10000, 1024,
                           mb * 128, nb * 128, sAh, sAl, sBh, sBl);
        }
        return;
    }

    // ---------------- recurrence (R12-exact math/publish) ----------------
    const int layer = blockIdx.x >> 6;
    const int n0    = (int)(blockIdx.x & 63) * 16;
    const int m0    = w * 16;
    const int rb    = lane & 15;
    const int q4    = lane >> 4;
    const int arow  = m0 + rb;
    const int srow  = tid >> 2;           // publish: row 0..63
    const int sc4   = (tid & 3) * 4;      // publish: col group

    if (layer == 0) {
        for (int i = 0; i < 16; ++i) {
            int s    = i * 256 + tid;
            int arr  = s >> 11;
            int r    = (s >> 7) & 15;
            int g    = s & 127;
            int slot = g ^ (r & 7);
            const u16* src = (arr ? Wh0l : Wh0h) + (size_t)(n0 + r) * 1024 + g * 8;
            *reinterpret_cast<int4*>(sW + arr * 16384 + r * 1024 + slot * 8) =
                *reinterpret_cast<const int4*>(src);
        }
    } else {
        for (int i = 0; i < 32; ++i) {
            int s    = i * 256 + tid;
            int arr  = s >> 12;
            int r    = (s >> 8) & 15;
            int g    = s & 255;
            int slot = g ^ (r & 7);
            const u16* src;
            if (g < 128) src = (arr ? Wx1l : Wx1h) + (size_t)(n0 + r) * 1024 + g * 8;
            else         src = (arr ? Wh1l : Wh1h) + (size_t)(n0 + r) * 1024 + (g - 128) * 8;
            *reinterpret_cast<int4*>(sW + arr * 32768 + r * 2048 + slot * 8) =
                *reinterpret_cast<const int4*>(src);
        }
    }
    __syncthreads();

    if (layer == 0) {
        for (int t = 0; t < 70; ++t) {
            if (t > 0) wait_count(flags + (t - 1), 64);
            const u16* hph = t ? H0h + (size_t)(t - 1) * BH : hs0h;
            const u16* hpl = t ? H0l + (size_t)(t - 1) * BH : hs0l;
            f32x4 acc = {0.f, 0.f, 0.f, 0.f};
            #pragma unroll 8
            for (int kt = 0; kt < 32; ++kt) {
                short8 ah = *reinterpret_cast<const short8*>(hph + (size_t)arow * 1024 + kt * 32 + q4 * 8);
                short8 al = *reinterpret_cast<const short8*>(hpl + (size_t)arow * 1024 + kt * 32 + q4 * 8);
                int slot = (kt * 4 + q4) ^ (rb & 7);
                short8 bh = *reinterpret_cast<const short8*>(sW + rb * 1024 + slot * 8);
                short8 bl = *reinterpret_cast<const short8*>(sW + 16384 + rb * 1024 + slot * 8);
                acc = MFMA_BF16(ah, bh, acc);
                acc = MFMA_BF16(ah, bl, acc);
                acc = MFMA_BF16(al, bh, acc);
            }
            #pragma unroll
            for (int r = 0; r < 4; ++r) {
                int m = m0 + q4 * 4 + r;
                size_t o = (size_t)t * BH + (size_t)m * 1024 + n0 + rb;
                sStage[m * 17 + rb] = tanhf(acc[r] + A0[o]);
            }
            __syncthreads();
            {
                float f0 = sStage[srow * 17 + sc4 + 0];
                float f1 = sStage[srow * 17 + sc4 + 1];
                float f2 = sStage[srow * 17 + sc4 + 2];
                float f3 = sStage[srow * 17 + sc4 + 3];
                u16 a,b,c,d, la,lb,lc,ld;
                split2(f0,a,la); split2(f1,b,lb); split2(f2,c,lc); split2(f3,d,ld);
                size_t o64 = ((size_t)t * BH + (size_t)srow * 1024 + n0 + sc4) >> 2;
                __hip_atomic_store((u64*)H0h + o64, pack4(a,b,c,d),
                                   __ATOMIC_RELAXED, __HIP_MEMORY_SCOPE_AGENT);
                __hip_atomic_store((u64*)H0l + o64, pack4(la,lb,lc,ld),
                                   __ATOMIC_RELAXED, __HIP_MEMORY_SCOPE_AGENT);
            }
            signal_done(flags + t);
        }
    } else {
        for (int t = 0; t < 70; ++t) {
            wait_count(flags + t, 64);
            if (t > 0) wait_count(flags + 70 + (t - 1), 64);
            const u16* h0h  = H0h + (size_t)t * BH;
            const u16* h0l  = H0l + (size_t)t * BH;
            const u16* h1ph = t ? H1h + (size_t)(t - 1) * BH : hs1h;
            const u16* h1pl = t ? H1l + (size_t)(t - 1) * BH : hs1l;
            f32x4 acc = {0.f, 0.f, 0.f, 0.f};
            #pragma unroll 8
            for (int kt = 0; kt < 32; ++kt) {
                short8 ah = *reinterpret_cast<const short8*>(h0h + (size_t)arow * 1024 + kt * 32 + q4 * 8);
                short8 al = *reinterpret_cast<const short8*>(h0l + (size_t)arow * 1024 + kt * 32 + q4 * 8);
                int slot = (kt * 4 + q4) ^ (rb & 7);
                short8 bh = *reinterpret_cast<const short8*>(sW + rb * 2048 + slot * 8);
                short8 bl = *reinterpret_cast<const short8*>(sW + 32768 + rb * 2048 + slot * 8);
                acc = MFMA_BF16(ah, bh, acc);
                acc = MFMA_BF16(ah, bl, acc);
                acc = MFMA_BF16(al, bh, acc);
            }
            #pragma unroll 8
            for (int kt = 32; kt < 64; ++kt) {
                int ko = (kt - 32) * 32;
                short8 ah = *reinterpret_cast<const short8*>(h1ph + (size_t)arow * 1024 + ko + q4 * 8);
                short8 al = *reinterpret_cast<const short8*>(h1pl + (size_t)arow * 1024 + ko + q4 * 8);
                int slot = (kt * 4 + q4) ^ (rb & 7);
                short8 bh = *reinterpret_cast<const short8*>(sW + rb * 2048 + slot * 8);
                short8 bl = *reinterpret_cast<const short8*>(sW + 32768 + rb * 2048 + slot * 8);
                acc = MFMA_BF16(ah, bh, acc);
                acc = MFMA_BF16(ah, bl, acc);
                acc = MFMA_BF16(al, bh, acc);
            }
            const int n = n0 + rb;
            #pragma unroll
            for (int r = 0; r < 4; ++r) {
                int m = m0 + q4 * 4 + r;
                sStage[m * 17 + rb] = tanhf(acc[r] + bh1[n]);
            }
            __syncthreads();
            {
                float f0 = sStage[srow * 17 + sc4 + 0];
                float f1 = sStage[srow * 17 + sc4 + 1];
                float f2 = sStage[srow * 17 + sc4 + 2];
                float f3 = sStage[srow * 17 + sc4 + 3];
                u16 a,b,c,d, la,lb,lc,ld;
                split2(f0,a,la); split2(f1,b,lb); split2(f2,c,lc); split2(f3,d,ld);
                size_t o64 = ((size_t)t * BH + (size_t)srow * 1024 + n0 + sc4) >> 2;
                __hip_atomic_store((u64*)H1h + o64, pack4(a,b,c,d),
                                   __ATOMIC_RELAXED, __HIP_MEMORY_SCOPE_AGENT);
                __hip_atomic_store((u64*)H1l + o64, pack4(la,lb,lc,ld),
                                   __ATOMIC_RELAXED, __HIP_MEMORY_SCOPE_AGENT);
            }
            signal_done_rel(flags + 70 + t);
        }
    }
}

// ---------------- h_final tail (hi+lo reconstruction) ----------------------
__global__ __launch_bounds__(256) void hfinal_kernel(
    const u16* __restrict__ H0h, const u16* __restrict__ H0l,
    const u16* __restrict__ H1h, const u16* __restrict__ H1l,
    float* __restrict__ outp)
{
    int i = blockIdx.x * 256 + threadIdx.x;
    outp[i]         = bf16_f(H0h[i]) + bf16_f(H0l[i]);
    outp[65536 + i] = bf16_f(H1h[i]) + bf16_f(H1l[i]);
}

extern "C" void kernel_launch(void* const* d_in, const int* in_sizes, int n_in,
                              void* d_out, int out_size, void* d_ws, size_t ws_size,
                              hipStream_t stream)
{
    const int*   inputs = (const int*)  d_in[0];
    const float* hidden = (const float*)d_in[1];
    const float* embW   = (const float*)d_in[2];
    const float* Wx0    = (const float*)d_in[3];
    const float* Wx1    = (const float*)d_in[4];
    const float* Wh0    = (const float*)d_in[5];
    const float* bh0    = (const float*)d_in[6];
    const float* Wh1    = (const float*)d_in[7];
    const float* bh1    = (const float*)d_in[8];
    const float* Wy     = (const float*)d_in[9];
    const float* by     = (const float*)d_in[10];
    float* out = (float*)d_out;

    const int T = 70, B = 64, V = 10000, E = 512, H = 1024;
    const int M = T * B;
    const size_t MH = (size_t)M * H;
    const size_t BH = (size_t)B * H;

    char* wsb = (char*)d_ws;
    u16*   Wyh  = (u16*)(wsb);
    u16*   Wyl  = Wyh + (size_t)V * H;
    float* buf0 = (float*)(wsb + 40960000);
    u16*   H0h  = (u16*)(wsb + 59310080);
    u16*   H0l  = H0h + MH;
    u16*   H1h  = H0l + MH;
    u16*   H1l  = H1h + MH;
    u16*   Wx0h = H1l + MH;
    u16*   Wx0l = Wx0h + (size_t)H * E;
    u16*   Wx1h = Wx0l + (size_t)H * E;
    u16*   Wx1l = Wx1h + (size_t)H * H;
    u16*   Wh0h = Wx1l + (size_t)H * H;
    u16*   Wh0l = Wh0h + (size_t)H * H;
    u16*   Wh1h = Wh0l + (size_t)H * H;
    u16*   Wh1l = Wh1h + (size_t)H * H;
    u16*   hs0h = Wh1l + (size_t)H * H;
    u16*   hs0l = hs0h + BH;
    u16*   hs1h = hs0l + BH;
    u16*   hs1l = hs1h + BH;
    // Flags in the Wx0l region (dead after the A0 GEMM; memset is
    // stream-ordered after it).  NOT in d_out: workers write logits there.
    int*   flags = (int*)(wsb + 97058816);

    // d_out aliased scratch: gathered emb splits only (dead after A0 GEMM).
    u16*   Agh   = (u16*)((char*)d_out + 20971520);
    u16*   Agl   = Agh + (size_t)M * E;

    dim3 blk(256);

    // fused splits + gather
    split_all_kernel<<<dim3(13713), blk, 0, stream>>>(
        Wx0, Wx0h, Wx0l, Wx1, Wx1h, Wx1l, Wh0, Wh0h, Wh0l,
        Wh1, Wh1h, Wh1l, Wy, Wyh, Wyl, hidden, hs0h, hs0l);
    gather_split_kernel<<<dim3((M*E)/1024), blk, 0, stream>>>(embW, inputs, Agh, Agl, (M*E)/4);

    // A0 = embsplit @ Wx0^T + bh0  (consumes Wx0h/Wx0l; then Wx0l is dead)
    gemm_mfma<<<dim3(H/128, M/128), blk, 0, stream>>>(
        Agh, Agl, Wx0h, Wx0l, bh0, buf0, M, H, E);

    // zero the flags (in the now-dead Wx0l region)
    hipMemsetAsync(flags, 0, 140 * sizeof(int), stream);

    // persistent recurrence + overlapped logits (256 blocks cooperative)
    {
        const float* A0p = buf0;
        void* args[] = {
            (void*)&A0p,
            (void*)&hs0h, (void*)&hs0l, (void*)&hs1h, (void*)&hs1l,
            (void*)&H0h,  (void*)&H0l,  (void*)&H1h,  (void*)&H1l,
            (void*)&Wh0h, (void*)&Wh0l, (void*)&Wx1h, (void*)&Wx1l,
            (void*)&Wh1h, (void*)&Wh1l, (void*)&bh1, (void*)&flags,
            (void*)&Wyh, (void*)&Wyl, (void*)&by, (void*)&out
        };
        hipLaunchCooperativeKernel(reinterpret_cast<void*>(rnn_persist5),
                                   dim3(256), blk, args, 0, stream);
    }

    hfinal_kernel<<<dim3(256), blk, 0, stream>>>(
        H0h + (size_t)(T-1) * BH, H0l + (size_t)(T-1) * BH,
        H1h + (size_t)(T-1) * BH, H1l + (size_t)(T-1) * BH,
        out + (size_t)M * V);
}

// Round 18
// 1542.837 us; speedup vs baseline: 1.0093x; 1.0093x over previous
//
#include <hip/hip_runtime.h>
#include <hip/hip_bf16.h>
#include <cmath>
#include <cstdint>

// ---------------------------------------------------------------------------
// Stacked 2-layer Elman RNN, bf16 hi/lo-split MFMA (3-pass) everywhere.
//   fused split_all: all weights + initial hidden -> bf16 hi/lo (1 launch)
//   gather_split: emb[inputs] -> bf16 hi/lo
//   A0 = embsplit @ Wx0^T + bh0                         (MFMA GEMM)
//   ONE persistent cooperative kernel (128 blocks), flag-synced (R7/R12
//   scheme -- best measured passing):
//     blocks 0-63  (layer 0): h0[t] = tanh(A0[t] + h0[t-1] @ Wh0^T)
//     blocks 64-127(layer 1): h1[t] = tanh(h0[t]@Wx1^T + h1[t-1]@Wh1^T + bh1)
//     weight slices LDS-resident; h published as packed u64 agent-scope
//     relaxed atomic stores (write-through); counters fetch_add after
//     __syncthreads drain; relaxed polls.
//   h_final = hi+lo of t=69;
//   logits = H1split @ Wy^T + by  (separate GEMM, XCD-aware bijective remap)
// NOTE: in-kernel logits overlap (R9-R11, R16-R17) abandoned -- a latent
// timing-dependent worker-consumption race produced deterministic failures
// in 4 of 5 attempts; this configuration is fully deterministic.
// ---------------------------------------------------------------------------

using u16 = unsigned short;
using u32 = unsigned int;
using u64 = unsigned long long;
typedef __attribute__((ext_vector_type(8))) short short8;  // bf16x8 MFMA frag
typedef __attribute__((ext_vector_type(4))) float f32x4;

#define MFMA_BF16(a, b, c) __builtin_amdgcn_mfma_f32_16x16x32_bf16((a), (b), (c), 0, 0, 0)

__device__ __forceinline__ u16 bf16_rne(float x) {
    u32 u = __float_as_uint(x);
    u32 r = u + 0x7FFFu + ((u >> 16) & 1u);
    return (u16)(r >> 16);
}
__device__ __forceinline__ float bf16_f(u16 h) {
    return __uint_as_float(((u32)h) << 16);
}
__device__ __forceinline__ void split2(float x, u16& hi, u16& lo) {
    hi = bf16_rne(x);
    lo = bf16_rne(x - bf16_f(hi));
}
__device__ __forceinline__ u64 pack4(u16 a, u16 b, u16 c, u16 d) {
    return (u64)a | ((u64)b << 16) | ((u64)c << 32) | ((u64)d << 48);
}

// ---- cross-workgroup sync (R7 scheme: relaxed, no fences) -----------------
__device__ __forceinline__ void wait_count(int* f, int target) {
    if (threadIdx.x == 0) {
        while (__hip_atomic_load(f, __ATOMIC_RELAXED, __HIP_MEMORY_SCOPE_AGENT) < target)
            __builtin_amdgcn_s_sleep(1);
    }
    __syncthreads();
}
__device__ __forceinline__ void signal_done(int* f) {
    __syncthreads();   // vmcnt(0): write-through h-stores drained
    if (threadIdx.x == 0)
        __hip_atomic_fetch_add(f, 1, __ATOMIC_RELAXED, __HIP_MEMORY_SCOPE_AGENT);
}

// ---------------- fused split: weights + hidden -> bf16 hi/lo --------------
__global__ __launch_bounds__(256) void split_all_kernel(
    const float* __restrict__ Wx0, u16* Wx0h, u16* Wx0l,
    const float* __restrict__ Wx1, u16* Wx1h, u16* Wx1l,
    const float* __restrict__ Wh0, u16* Wh0h, u16* Wh0l,
    const float* __restrict__ Wh1, u16* Wh1h, u16* Wh1l,
    const float* __restrict__ Wy,  u16* Wyh,  u16* Wyl,
    const float* __restrict__ hid, u16* hsh,  u16* hsl)
{
    const int n0 = 131072;    // Wx0: 1024*512/4
    const int n1 = 262144;    // Wx1
    const int n2 = 262144;    // Wh0
    const int n3 = 262144;    // Wh1
    const int n4s = 2560000;  // Wy
    const int n5 = 32768;     // hidden (both layers; contiguous dst in ws)
    int g = blockIdx.x * 256 + threadIdx.x;
    const float* src; u16* hi; u16* lo; int off;
    if      (g < n0)                       { src=Wx0; hi=Wx0h; lo=Wx0l; off=g; }
    else if ((g -= n0) < n1)               { src=Wx1; hi=Wx1h; lo=Wx1l; off=g; }
    else if ((g -= n1) < n2)               { src=Wh0; hi=Wh0h; lo=Wh0l; off=g; }
    else if ((g -= n2) < n3)               { src=Wh1; hi=Wh1h; lo=Wh1l; off=g; }
    else if ((g -= n3) < n4s)              { src=Wy;  hi=Wyh;  lo=Wyl;  off=g; }
    else if ((g -= n4s) < n5)              { src=hid; hi=hsh;  lo=hsl;  off=g; }
    else return;
    float4 v = *reinterpret_cast<const float4*>(src + (size_t)off * 4);
    u16 h0,h1,h2,h3,l0,l1,l2,l3;
    split2(v.x,h0,l0); split2(v.y,h1,l1); split2(v.z,h2,l2); split2(v.w,h3,l3);
    ushort4 H = {h0,h1,h2,h3}, L = {l0,l1,l2,l3};
    *reinterpret_cast<ushort4*>(hi + (size_t)off * 4) = H;
    *reinterpret_cast<ushort4*>(lo + (size_t)off * 4) = L;
}

// ---------------- fused gather(emb, idx) + split:  out [M][512] -------------
__global__ __launch_bounds__(256) void gather_split_kernel(
    const float* __restrict__ emb, const int* __restrict__ idx,
    u16* __restrict__ hi, u16* __restrict__ lo, int n4)
{
    int g = blockIdx.x * 256 + threadIdx.x;
    if (g >= n4) return;
    int m  = g >> 7;
    int c4 = g & 127;
    const float* src = emb + (size_t)idx[m] * 512 + c4 * 4;
    float4 v = *reinterpret_cast<const float4*>(src);
    u16 h0,h1,h2,h3,l0,l1,l2,l3;
    split2(v.x,h0,l0); split2(v.y,h1,l1); split2(v.z,h2,l2); split2(v.w,h3,l3);
    ushort4 H = {h0,h1,h2,h3}, L = {l0,l1,l2,l3};
    size_t o = (size_t)m * 512 + c4 * 4;
    *reinterpret_cast<ushort4*>(hi + o) = H;
    *reinterpret_cast<ushort4*>(lo + o) = L;
}

// ---------------- bf16-split MFMA GEMM tile body (device) ------------------
// C[m0:m0+128, n0:n0+128] = A @ B^T + bias for row-major A[M][K], B[N][K].
__device__ __forceinline__ void gemm_tile(
    const u16* __restrict__ Ah, const u16* __restrict__ Al,
    const u16* __restrict__ Bh, const u16* __restrict__ Bl,
    const float* __restrict__ bias, float* __restrict__ C,
    int N, int K, int m0, int n0,
    u16* sAh, u16* sAl, u16* sBh, u16* sBl)
{
    const int tid  = threadIdx.x;
    const int lane = tid & 63;
    const int w    = tid >> 6;
    const int wr   = w >> 1, wc = w & 1;

    f32x4 acc[4][4];
    #pragma unroll
    for (int i = 0; i < 4; ++i)
        #pragma unroll
        for (int j = 0; j < 4; ++j) acc[i][j] = 0.0f;

    for (int k0 = 0; k0 < K; k0 += 32) {
        #pragma unroll
        for (int r = 0; r < 2; ++r) {
            int s   = r * 256 + tid;
            int row = s >> 2, q = s & 3;
            int gq  = q ^ (row & 3);
            int l16 = row * 32 + q * 8;
            size_t ga = (size_t)(m0 + row) * K + k0 + gq * 8;
            int brow = n0 + row; if (brow >= N) brow = N - 1;
            size_t gb = (size_t)brow * K + k0 + gq * 8;
            *reinterpret_cast<int4*>(sAh + l16) = *reinterpret_cast<const int4*>(Ah + ga);
            *reinterpret_cast<int4*>(sAl + l16) = *reinterpret_cast<const int4*>(Al + ga);
            *reinterpret_cast<int4*>(sBh + l16) = *reinterpret_cast<const int4*>(Bh + gb);
            *reinterpret_cast<int4*>(sBl + l16) = *reinterpret_cast<const int4*>(Bl + gb);
        }
        __syncthreads();

        const int q4 = lane >> 4;
        short8 afh[4], afl[4];
        #pragma unroll
        for (int i = 0; i < 4; ++i) {
            int ra  = wr * 64 + i * 16 + (lane & 15);
            int off = ra * 32 + (q4 ^ (ra & 3)) * 8;
            afh[i] = *reinterpret_cast<const short8*>(sAh + off);
            afl[i] = *reinterpret_cast<const short8*>(sAl + off);
        }
        #pragma unroll
        for (int j = 0; j < 4; ++j) {
            int rb  = wc * 64 + j * 16 + (lane & 15);
            int off = rb * 32 + (q4 ^ (rb & 3)) * 8;
            short8 bfh = *reinterpret_cast<const short8*>(sBh + off);
            short8 bfl = *reinterpret_cast<const short8*>(sBl + off);
            #pragma unroll
            for (int i = 0; i < 4; ++i) {
                acc[i][j] = MFMA_BF16(afh[i], bfh, acc[i][j]);
                acc[i][j] = MFMA_BF16(afh[i], bfl, acc[i][j]);
                acc[i][j] = MFMA_BF16(afl[i], bfh, acc[i][j]);
            }
        }
        __syncthreads();
    }

    #pragma unroll
    for (int j = 0; j < 4; ++j) {
        int n = n0 + wc * 64 + j * 16 + (lane & 15);
        if (n < N) {
            float bv = bias[n];
            #pragma unroll
            for (int i = 0; i < 4; ++i) {
                #pragma unroll
                for (int r = 0; r < 4; ++r) {
                    int m = m0 + wr * 64 + i * 16 + (lane >> 4) * 4 + r;
                    C[(size_t)m * N + n] = acc[i][j][r] + bv;
                }
            }
        }
    }
}

// ---------------- standalone GEMM (A0 prologue) ----------------------------
__global__ __launch_bounds__(256) void gemm_mfma(
    const u16* __restrict__ Ah, const u16* __restrict__ Al,
    const u16* __restrict__ Bh, const u16* __restrict__ Bl,
    const float* __restrict__ bias, float* __restrict__ C,
    int M, int N, int K)
{
    __shared__ u16 sAh[128*32], sAl[128*32], sBh[128*32], sBl[128*32];
    gemm_tile(Ah, Al, Bh, Bl, bias, C, N, K,
              blockIdx.y * 128, blockIdx.x * 128, sAh, sAl, sBh, sBl);
}

// ---------------- logits GEMM with XCD-aware bijective block remap ---------
__global__ __launch_bounds__(256) void gemm_mfma_swz(
    const u16* __restrict__ Ah, const u16* __restrict__ Al,
    const u16* __restrict__ Bh, const u16* __restrict__ Bl,
    const float* __restrict__ bias, float* __restrict__ C,
    int M, int N, int K)
{
    __shared__ u16 sAh[128*32], sAl[128*32], sBh[128*32], sBl[128*32];
    const int NTN = 79;                       // ceil(10000/128)
    const int nwg = 35 * 79;                  // 2765
    const int q = nwg / 8, r = nwg % 8;       // 345, 5
    int orig = (int)blockIdx.x;
    int xcd  = orig % 8;
    int idx  = orig / 8;
    int wg   = (xcd < r) ? (xcd * (q + 1) + idx)
                         : (r * (q + 1) + (xcd - r) * q + idx);
    int mb = wg / NTN, nb = wg % NTN;
    gemm_tile(Ah, Al, Bh, Bl, bias, C, N, K,
              mb * 128, nb * 128, sAh, sAl, sBh, sBl);
}

// ---------------- persistent recurrence kernel (R12 exact) -----------------
// 128 blocks x 256 threads, cooperative (co-residency), NO grid.sync.
// flags[0..69]  = # layer-0 blocks done with h0[t]
// flags[70..139]= # layer-1 blocks done with h1[t]
__global__ __launch_bounds__(256, 1) void rnn_persist2(
    const float* __restrict__ A0,
    const u16* __restrict__ hs0h, const u16* __restrict__ hs0l,
    const u16* __restrict__ hs1h, const u16* __restrict__ hs1l,
    u16* __restrict__ H0h, u16* __restrict__ H0l,
    u16* __restrict__ H1h, u16* __restrict__ H1l,
    const u16* __restrict__ Wh0h, const u16* __restrict__ Wh0l,
    const u16* __restrict__ Wx1h, const u16* __restrict__ Wx1l,
    const u16* __restrict__ Wh1h, const u16* __restrict__ Wh1l,
    const float* __restrict__ bh1, int* flags)
{
    __shared__ u16 sW[65536];          // 128 KiB: [hi | lo] halves
    __shared__ float sStage[64 * 17];  // h-tile staging (pad 17 vs bank conflicts)
    const int tid   = threadIdx.x;
    const int lane  = tid & 63;
    const int w     = tid >> 6;
    const int layer = blockIdx.x >> 6;
    const int n0    = (int)(blockIdx.x & 63) * 16;
    const int m0    = w * 16;
    const int rb    = lane & 15;
    const int q4    = lane >> 4;
    const int arow  = m0 + rb;
    const size_t BH = 65536;
    const int srow  = tid >> 2;           // store phase: row 0..63
    const int sc4   = (tid & 3) * 4;      // store phase: col group

    // ---- stage weight slice into LDS, XOR-swizzled on 16B quads ----
    if (layer == 0) {
        for (int i = 0; i < 16; ++i) {
            int s    = i * 256 + tid;
            int arr  = s >> 11;
            int r    = (s >> 7) & 15;
            int g    = s & 127;
            int slot = g ^ (r & 7);
            const u16* src = (arr ? Wh0l : Wh0h) + (size_t)(n0 + r) * 1024 + g * 8;
            *reinterpret_cast<int4*>(sW + arr * 16384 + r * 1024 + slot * 8) =
                *reinterpret_cast<const int4*>(src);
        }
    } else {
        for (int i = 0; i < 32; ++i) {
            int s    = i * 256 + tid;
            int arr  = s >> 12;
            int r    = (s >> 8) & 15;
            int g    = s & 255;
            int slot = g ^ (r & 7);
            const u16* src;
            if (g < 128) src = (arr ? Wx1l : Wx1h) + (size_t)(n0 + r) * 1024 + g * 8;
            else         src = (arr ? Wh1l : Wh1h) + (size_t)(n0 + r) * 1024 + (g - 128) * 8;
            *reinterpret_cast<int4*>(sW + arr * 32768 + r * 2048 + slot * 8) =
                *reinterpret_cast<const int4*>(src);
        }
    }
    __syncthreads();

    if (layer == 0) {
        for (int t = 0; t < 70; ++t) {
            if (t > 0) wait_count(flags + (t - 1), 64);
            const u16* hph = t ? H0h + (size_t)(t - 1) * BH : hs0h;
            const u16* hpl = t ? H0l + (size_t)(t - 1) * BH : hs0l;
            f32x4 acc = {0.f, 0.f, 0.f, 0.f};
            #pragma unroll 8
            for (int kt = 0; kt < 32; ++kt) {
                short8 ah = *reinterpret_cast<const short8*>(hph + (size_t)arow * 1024 + kt * 32 + q4 * 8);
                short8 al = *reinterpret_cast<const short8*>(hpl + (size_t)arow * 1024 + kt * 32 + q4 * 8);
                int slot = (kt * 4 + q4) ^ (rb & 7);
                short8 bh = *reinterpret_cast<const short8*>(sW + rb * 1024 + slot * 8);
                short8 bl = *reinterpret_cast<const short8*>(sW + 16384 + rb * 1024 + slot * 8);
                acc = MFMA_BF16(ah, bh, acc);
                acc = MFMA_BF16(ah, bl, acc);
                acc = MFMA_BF16(al, bh, acc);
            }
            #pragma unroll
            for (int r = 0; r < 4; ++r) {
                int m = m0 + q4 * 4 + r;
                size_t o = (size_t)t * BH + (size_t)m * 1024 + n0 + rb;
                sStage[m * 17 + rb] = tanhf(acc[r] + A0[o]);
            }
            __syncthreads();
            {
                float f0 = sStage[srow * 17 + sc4 + 0];
                float f1 = sStage[srow * 17 + sc4 + 1];
                float f2 = sStage[srow * 17 + sc4 + 2];
                float f3 = sStage[srow * 17 + sc4 + 3];
                u16 a,b,c,d, la,lb,lc,ld;
                split2(f0,a,la); split2(f1,b,lb); split2(f2,c,lc); split2(f3,d,ld);
                size_t o64 = ((size_t)t * BH + (size_t)srow * 1024 + n0 + sc4) >> 2;
                __hip_atomic_store((u64*)H0h + o64, pack4(a,b,c,d),
                                   __ATOMIC_RELAXED, __HIP_MEMORY_SCOPE_AGENT);
                __hip_atomic_store((u64*)H0l + o64, pack4(la,lb,lc,ld),
                                   __ATOMIC_RELAXED, __HIP_MEMORY_SCOPE_AGENT);
            }
            signal_done(flags + t);
        }
    } else {
        for (int t = 0; t < 70; ++t) {
            wait_count(flags + t, 64);
            if (t > 0) wait_count(flags + 70 + (t - 1), 64);
            const u16* h0h  = H0h + (size_t)t * BH;
            const u16* h0l  = H0l + (size_t)t * BH;
            const u16* h1ph = t ? H1h + (size_t)(t - 1) * BH : hs1h;
            const u16* h1pl = t ? H1l + (size_t)(t - 1) * BH : hs1l;
            f32x4 acc = {0.f, 0.f, 0.f, 0.f};
            #pragma unroll 8
            for (int kt = 0; kt < 32; ++kt) {
                short8 ah = *reinterpret_cast<const short8*>(h0h + (size_t)arow * 1024 + kt * 32 + q4 * 8);
                short8 al = *reinterpret_cast<const short8*>(h0l + (size_t)arow * 1024 + kt * 32 + q4 * 8);
                int slot = (kt * 4 + q4) ^ (rb & 7);
                short8 bh = *reinterpret_cast<const short8*>(sW + rb * 2048 + slot * 8);
                short8 bl = *reinterpret_cast<const short8*>(sW + 32768 + rb * 2048 + slot * 8);
                acc = MFMA_BF16(ah, bh, acc);
                acc = MFMA_BF16(ah, bl, acc);
                acc = MFMA_BF16(al, bh, acc);
            }
            #pragma unroll 8
            for (int kt = 32; kt < 64; ++kt) {
                int ko = (kt - 32) * 32;
                short8 ah = *reinterpret_cast<const short8*>(h1ph + (size_t)arow * 1024 + ko + q4 * 8);
                short8 al = *reinterpret_cast<const short8*>(h1pl + (size_t)arow * 1024 + ko + q4 * 8);
                int slot = (kt * 4 + q4) ^ (rb & 7);
                short8 bh = *reinterpret_cast<const short8*>(sW + rb * 2048 + slot * 8);
                short8 bl = *reinterpret_cast<const short8*>(sW + 32768 + rb * 2048 + slot * 8);
                acc = MFMA_BF16(ah, bh, acc);
                acc = MFMA_BF16(ah, bl, acc);
                acc = MFMA_BF16(al, bh, acc);
            }
            const int n = n0 + rb;
            #pragma unroll
            for (int r = 0; r < 4; ++r) {
                int m = m0 + q4 * 4 + r;
                sStage[m * 17 + rb] = tanhf(acc[r] + bh1[n]);
            }
            __syncthreads();
            {
                float f0 = sStage[srow * 17 + sc4 + 0];
                float f1 = sStage[srow * 17 + sc4 + 1];
                float f2 = sStage[srow * 17 + sc4 + 2];
                float f3 = sStage[srow * 17 + sc4 + 3];
                u16 a,b,c,d, la,lb,lc,ld;
                split2(f0,a,la); split2(f1,b,lb); split2(f2,c,lc); split2(f3,d,ld);
                size_t o64 = ((size_t)t * BH + (size_t)srow * 1024 + n0 + sc4) >> 2;
                __hip_atomic_store((u64*)H1h + o64, pack4(a,b,c,d),
                                   __ATOMIC_RELAXED, __HIP_MEMORY_SCOPE_AGENT);
                __hip_atomic_store((u64*)H1l + o64, pack4(la,lb,lc,ld),
                                   __ATOMIC_RELAXED, __HIP_MEMORY_SCOPE_AGENT);
            }
            signal_done(flags + 70 + t);
        }
    }
}

// ---------------- h_final tail (hi+lo reconstruction) ----------------------
__global__ __launch_bounds__(256) void hfinal_kernel(
    const u16* __restrict__ H0h, const u16* __restrict__ H0l,
    const u16* __restrict__ H1h, const u16* __restrict__ H1l,
    float* __restrict__ outp)
{
    int i = blockIdx.x * 256 + threadIdx.x;
    outp[i]         = bf16_f(H0h[i]) + bf16_f(H0l[i]);
    outp[65536 + i] = bf16_f(H1h[i]) + bf16_f(H1l[i]);
}

extern "C" void kernel_launch(void* const* d_in, const int* in_sizes, int n_in,
                              void* d_out, int out_size, void* d_ws, size_t ws_size,
                              hipStream_t stream)
{
    const int*   inputs = (const int*)  d_in[0];
    const float* hidden = (const float*)d_in[1];
    const float* embW   = (const float*)d_in[2];
    const float* Wx0    = (const float*)d_in[3];
    const float* Wx1    = (const float*)d_in[4];
    const float* Wh0    = (const float*)d_in[5];
    const float* bh0    = (const float*)d_in[6];
    const float* Wh1    = (const float*)d_in[7];
    const float* bh1    = (const float*)d_in[8];
    const float* Wy     = (const float*)d_in[9];
    const float* by     = (const float*)d_in[10];
    float* out = (float*)d_out;

    const int T = 70, B = 64, V = 10000, E = 512, H = 1024;
    const int M = T * B;
    const size_t MH = (size_t)M * H;
    const size_t BH = (size_t)B * H;

    char* wsb = (char*)d_ws;
    u16*   Wyh  = (u16*)(wsb);
    u16*   Wyl  = Wyh + (size_t)V * H;
    float* buf0 = (float*)(wsb + 40960000);
    u16*   H0h  = (u16*)(wsb + 59310080);
    u16*   H0l  = H0h + MH;
    u16*   H1h  = H0l + MH;
    u16*   H1l  = H1h + MH;
    u16*   Wx0h = H1l + MH;
    u16*   Wx0l = Wx0h + (size_t)H * E;
    u16*   Wx1h = Wx0l + (size_t)H * E;
    u16*   Wx1l = Wx1h + (size_t)H * H;
    u16*   Wh0h = Wx1l + (size_t)H * H;
    u16*   Wh0l = Wh0h + (size_t)H * H;
    u16*   Wh1h = Wh0l + (size_t)H * H;
    u16*   Wh1l = Wh1h + (size_t)H * H;
    u16*   hs0h = Wh1l + (size_t)H * H;
    u16*   hs0l = hs0h + BH;
    u16*   hs1h = hs0l + BH;
    u16*   hs1l = hs1h + BH;

    // d_out aliased scratch: gathered emb splits (dead after A0 GEMM) and
    // sync flags (dead after persist; overwritten by logits afterwards).
    u16*   Agh   = (u16*)((char*)d_out + 20971520);
    u16*   Agl   = Agh + (size_t)M * E;
    int*   flags = (int*)((char*)d_out + 104857600);   // +100 MB, 140 ints

    dim3 blk(256);

    hipMemsetAsync(flags, 0, 140 * sizeof(int), stream);

    // fused splits: all weights + both hidden layers in one launch.
    split_all_kernel<<<dim3(13713), blk, 0, stream>>>(
        Wx0, Wx0h, Wx0l,
        Wx1, Wx1h, Wx1l,
        Wh0, Wh0h, Wh0l,
        Wh1, Wh1h, Wh1l,
        Wy,  Wyh,  Wyl,
        hidden, hs0h, hs0l);   // hidden dst is contiguous: hs0h/hs0l then
                               // hs1h/hs1l follow in the ws layout
    gather_split_kernel<<<dim3((M*E)/1024), blk, 0, stream>>>(embW, inputs, Agh, Agl, (M*E)/4);

    // A0 = embsplit @ Wx0^T + bh0
    gemm_mfma<<<dim3(H/128, M/128), blk, 0, stream>>>(
        Agh, Agl, Wx0h, Wx0l, bh0, buf0, M, H, E);

    // persistent recurrence, flag-synced (R12 exact)
    {
        const float* A0p = buf0;
        void* args[] = {
            (void*)&A0p,
            (void*)&hs0h, (void*)&hs0l, (void*)&hs1h, (void*)&hs1l,
            (void*)&H0h,  (void*)&H0l,  (void*)&H1h,  (void*)&H1l,
            (void*)&Wh0h, (void*)&Wh0l, (void*)&Wx1h, (void*)&Wx1l,
            (void*)&Wh1h, (void*)&Wh1l, (void*)&bh1, (void*)&flags
        };
        hipLaunchCooperativeKernel(reinterpret_cast<void*>(rnn_persist2),
                                   dim3(128), blk, args, 0, stream);
    }

    hfinal_kernel<<<dim3(256), blk, 0, stream>>>(
        H0h + (size_t)(T-1) * BH, H0l + (size_t)(T-1) * BH,
        H1h + (size_t)(T-1) * BH, H1l + (size_t)(T-1) * BH,
        out + (size_t)M * V);

    // logits = H1split @ Wy^T + by   (XCD-aware bijective block remap)
    gemm_mfma_swz<<<dim3(35 * 79), blk, 0, stream>>>(
        H1h, H1l, Wyh, Wyl, by, out, M, V, H);
}

// Round 20
// 1538.310 us; speedup vs baseline: 1.0122x; 1.0029x over previous
//
#include <hip/hip_runtime.h>
#include <hip/hip_bf16.h>
#include <cmath>
#include <cstdint>

// ---------------------------------------------------------------------------
// Stacked 2-layer Elman RNN, bf16 hi/lo-split MFMA (3-pass) everywhere.
//   fused split_all: all weights + initial hidden -> bf16 hi/lo (1 launch)
//   gather_split: emb[inputs] -> bf16 hi/lo
//   A0 = embsplit @ Wx0^T + bh0                         (MFMA GEMM)
//   ONE persistent cooperative kernel (128 blocks), flag-synced (R7/R12
//   scheme -- best measured passing):
//     blocks 0-63  (layer 0): h0[t] = tanh(A0[t] + h0[t-1] @ Wh0^T)
//     blocks 64-127(layer 1): h1[t] = tanh(h0[t]@Wx1^T + h1[t-1]@Wh1^T + bh1)
//     weight slices LDS-resident; h published as packed u64 agent-scope
//     relaxed atomic stores (write-through); counters fetch_add after
//     __syncthreads drain; relaxed polls.
//   h_final = hi+lo of t=69;
//   logits = H1split @ Wy^T + by  (separate GEMM, XCD-aware bijective remap)
// NOTE: in-kernel logits overlap (R9-R11, R16-R17, R19) permanently
// abandoned -- a consumption-ordering mechanism on the multi-XCD path
// defeats every publication scheme tested (6 attempts, 5 deterministic
// failures).  This configuration is fully deterministic (green 3x).
// ---------------------------------------------------------------------------

using u16 = unsigned short;
using u32 = unsigned int;
using u64 = unsigned long long;
typedef __attribute__((ext_vector_type(8))) short short8;  // bf16x8 MFMA frag
typedef __attribute__((ext_vector_type(4))) float f32x4;

#define MFMA_BF16(a, b, c) __builtin_amdgcn_mfma_f32_16x16x32_bf16((a), (b), (c), 0, 0, 0)

__device__ __forceinline__ u16 bf16_rne(float x) {
    u32 u = __float_as_uint(x);
    u32 r = u + 0x7FFFu + ((u >> 16) & 1u);
    return (u16)(r >> 16);
}
__device__ __forceinline__ float bf16_f(u16 h) {
    return __uint_as_float(((u32)h) << 16);
}
__device__ __forceinline__ void split2(float x, u16& hi, u16& lo) {
    hi = bf16_rne(x);
    lo = bf16_rne(x - bf16_f(hi));
}
__device__ __forceinline__ u64 pack4(u16 a, u16 b, u16 c, u16 d) {
    return (u64)a | ((u64)b << 16) | ((u64)c << 32) | ((u64)d << 48);
}

// ---- cross-workgroup sync (R7 scheme: relaxed, no fences) -----------------
__device__ __forceinline__ void wait_count(int* f, int target) {
    if (threadIdx.x == 0) {
        while (__hip_atomic_load(f, __ATOMIC_RELAXED, __HIP_MEMORY_SCOPE_AGENT) < target)
            __builtin_amdgcn_s_sleep(1);
    }
    __syncthreads();
}
__device__ __forceinline__ void signal_done(int* f) {
    __syncthreads();   // vmcnt(0): write-through h-stores drained
    if (threadIdx.x == 0)
        __hip_atomic_fetch_add(f, 1, __ATOMIC_RELAXED, __HIP_MEMORY_SCOPE_AGENT);
}

// ---------------- fused split: weights + hidden -> bf16 hi/lo --------------
__global__ __launch_bounds__(256) void split_all_kernel(
    const float* __restrict__ Wx0, u16* Wx0h, u16* Wx0l,
    const float* __restrict__ Wx1, u16* Wx1h, u16* Wx1l,
    const float* __restrict__ Wh0, u16* Wh0h, u16* Wh0l,
    const float* __restrict__ Wh1, u16* Wh1h, u16* Wh1l,
    const float* __restrict__ Wy,  u16* Wyh,  u16* Wyl,
    const float* __restrict__ hid, u16* hsh,  u16* hsl)
{
    const int n0 = 131072;    // Wx0: 1024*512/4
    const int n1 = 262144;    // Wx1
    const int n2 = 262144;    // Wh0
    const int n3 = 262144;    // Wh1
    const int n4s = 2560000;  // Wy
    const int n5 = 32768;     // hidden (both layers; contiguous dst in ws)
    int g = blockIdx.x * 256 + threadIdx.x;
    const float* src; u16* hi; u16* lo; int off;
    if      (g < n0)                       { src=Wx0; hi=Wx0h; lo=Wx0l; off=g; }
    else if ((g -= n0) < n1)               { src=Wx1; hi=Wx1h; lo=Wx1l; off=g; }
    else if ((g -= n1) < n2)               { src=Wh0; hi=Wh0h; lo=Wh0l; off=g; }
    else if ((g -= n2) < n3)               { src=Wh1; hi=Wh1h; lo=Wh1l; off=g; }
    else if ((g -= n3) < n4s)              { src=Wy;  hi=Wyh;  lo=Wyl;  off=g; }
    else if ((g -= n4s) < n5)              { src=hid; hi=hsh;  lo=hsl;  off=g; }
    else return;
    float4 v = *reinterpret_cast<const float4*>(src + (size_t)off * 4);
    u16 h0,h1,h2,h3,l0,l1,l2,l3;
    split2(v.x,h0,l0); split2(v.y,h1,l1); split2(v.z,h2,l2); split2(v.w,h3,l3);
    ushort4 H = {h0,h1,h2,h3}, L = {l0,l1,l2,l3};
    *reinterpret_cast<ushort4*>(hi + (size_t)off * 4) = H;
    *reinterpret_cast<ushort4*>(lo + (size_t)off * 4) = L;
}

// ---------------- fused gather(emb, idx) + split:  out [M][512] -------------
__global__ __launch_bounds__(256) void gather_split_kernel(
    const float* __restrict__ emb, const int* __restrict__ idx,
    u16* __restrict__ hi, u16* __restrict__ lo, int n4)
{
    int g = blockIdx.x * 256 + threadIdx.x;
    if (g >= n4) return;
    int m  = g >> 7;
    int c4 = g & 127;
    const float* src = emb + (size_t)idx[m] * 512 + c4 * 4;
    float4 v = *reinterpret_cast<const float4*>(src);
    u16 h0,h1,h2,h3,l0,l1,l2,l3;
    split2(v.x,h0,l0); split2(v.y,h1,l1); split2(v.z,h2,l2); split2(v.w,h3,l3);
    ushort4 H = {h0,h1,h2,h3}, L = {l0,l1,l2,l3};
    size_t o = (size_t)m * 512 + c4 * 4;
    *reinterpret_cast<ushort4*>(hi + o) = H;
    *reinterpret_cast<ushort4*>(lo + o) = L;
}

// ---------------- bf16-split MFMA GEMM tile body (device) ------------------
// C[m0:m0+128, n0:n0+128] = A @ B^T + bias for row-major A[M][K], B[N][K].
__device__ __forceinline__ void gemm_tile(
    const u16* __restrict__ Ah, const u16* __restrict__ Al,
    const u16* __restrict__ Bh, const u16* __restrict__ Bl,
    const float* __restrict__ bias, float* __restrict__ C,
    int N, int K, int m0, int n0,
    u16* sAh, u16* sAl, u16* sBh, u16* sBl)
{
    const int tid  = threadIdx.x;
    const int lane = tid & 63;
    const int w    = tid >> 6;
    const int wr   = w >> 1, wc = w & 1;

    f32x4 acc[4][4];
    #pragma unroll
    for (int i = 0; i < 4; ++i)
        #pragma unroll
        for (int j = 0; j < 4; ++j) acc[i][j] = 0.0f;

    for (int k0 = 0; k0 < K; k0 += 32) {
        #pragma unroll
        for (int r = 0; r < 2; ++r) {
            int s   = r * 256 + tid;
            int row = s >> 2, q = s & 3;
            int gq  = q ^ (row & 3);
            int l16 = row * 32 + q * 8;
            size_t ga = (size_t)(m0 + row) * K + k0 + gq * 8;
            int brow = n0 + row; if (brow >= N) brow = N - 1;
            size_t gb = (size_t)brow * K + k0 + gq * 8;
            *reinterpret_cast<int4*>(sAh + l16) = *reinterpret_cast<const int4*>(Ah + ga);
            *reinterpret_cast<int4*>(sAl + l16) = *reinterpret_cast<const int4*>(Al + ga);
            *reinterpret_cast<int4*>(sBh + l16) = *reinterpret_cast<const int4*>(Bh + gb);
            *reinterpret_cast<int4*>(sBl + l16) = *reinterpret_cast<const int4*>(Bl + gb);
        }
        __syncthreads();

        const int q4 = lane >> 4;
        short8 afh[4], afl[4];
        #pragma unroll
        for (int i = 0; i < 4; ++i) {
            int ra  = wr * 64 + i * 16 + (lane & 15);
            int off = ra * 32 + (q4 ^ (ra & 3)) * 8;
            afh[i] = *reinterpret_cast<const short8*>(sAh + off);
            afl[i] = *reinterpret_cast<const short8*>(sAl + off);
        }
        #pragma unroll
        for (int j = 0; j < 4; ++j) {
            int rb  = wc * 64 + j * 16 + (lane & 15);
            int off = rb * 32 + (q4 ^ (rb & 3)) * 8;
            short8 bfh = *reinterpret_cast<const short8*>(sBh + off);
            short8 bfl = *reinterpret_cast<const short8*>(sBl + off);
            #pragma unroll
            for (int i = 0; i < 4; ++i) {
                acc[i][j] = MFMA_BF16(afh[i], bfh, acc[i][j]);
                acc[i][j] = MFMA_BF16(afh[i], bfl, acc[i][j]);
                acc[i][j] = MFMA_BF16(afl[i], bfh, acc[i][j]);
            }
        }
        __syncthreads();
    }

    #pragma unroll
    for (int j = 0; j < 4; ++j) {
        int n = n0 + wc * 64 + j * 16 + (lane & 15);
        if (n < N) {
            float bv = bias[n];
            #pragma unroll
            for (int i = 0; i < 4; ++i) {
                #pragma unroll
                for (int r = 0; r < 4; ++r) {
                    int m = m0 + wr * 64 + i * 16 + (lane >> 4) * 4 + r;
                    C[(size_t)m * N + n] = acc[i][j][r] + bv;
                }
            }
        }
    }
}

// ---------------- standalone GEMM (A0 prologue) ----------------------------
__global__ __launch_bounds__(256) void gemm_mfma(
    const u16* __restrict__ Ah, const u16* __restrict__ Al,
    const u16* __restrict__ Bh, const u16* __restrict__ Bl,
    const float* __restrict__ bias, float* __restrict__ C,
    int M, int N, int K)
{
    __shared__ u16 sAh[128*32], sAl[128*32], sBh[128*32], sBl[128*32];
    gemm_tile(Ah, Al, Bh, Bl, bias, C, N, K,
              blockIdx.y * 128, blockIdx.x * 128, sAh, sAl, sBh, sBl);
}

// ---------------- logits GEMM with XCD-aware bijective block remap ---------
__global__ __launch_bounds__(256) void gemm_mfma_swz(
    const u16* __restrict__ Ah, const u16* __restrict__ Al,
    const u16* __restrict__ Bh, const u16* __restrict__ Bl,
    const float* __restrict__ bias, float* __restrict__ C,
    int M, int N, int K)
{
    __shared__ u16 sAh[128*32], sAl[128*32], sBh[128*32], sBl[128*32];
    const int NTN = 79;                       // ceil(10000/128)
    const int nwg = 35 * 79;                  // 2765
    const int q = nwg / 8, r = nwg % 8;       // 345, 5
    int orig = (int)blockIdx.x;
    int xcd  = orig % 8;
    int idx  = orig / 8;
    int wg   = (xcd < r) ? (xcd * (q + 1) + idx)
                         : (r * (q + 1) + (xcd - r) * q + idx);
    int mb = wg / NTN, nb = wg % NTN;
    gemm_tile(Ah, Al, Bh, Bl, bias, C, N, K,
              mb * 128, nb * 128, sAh, sAl, sBh, sBl);
}

// ---------------- persistent recurrence kernel (R12 exact) -----------------
// 128 blocks x 256 threads, cooperative (co-residency), NO grid.sync.
// flags[0..69]  = # layer-0 blocks done with h0[t]
// flags[70..139]= # layer-1 blocks done with h1[t]
__global__ __launch_bounds__(256, 1) void rnn_persist2(
    const float* __restrict__ A0,
    const u16* __restrict__ hs0h, const u16* __restrict__ hs0l,
    const u16* __restrict__ hs1h, const u16* __restrict__ hs1l,
    u16* __restrict__ H0h, u16* __restrict__ H0l,
    u16* __restrict__ H1h, u16* __restrict__ H1l,
    const u16* __restrict__ Wh0h, const u16* __restrict__ Wh0l,
    const u16* __restrict__ Wx1h, const u16* __restrict__ Wx1l,
    const u16* __restrict__ Wh1h, const u16* __restrict__ Wh1l,
    const float* __restrict__ bh1, int* flags)
{
    __shared__ u16 sW[65536];          // 128 KiB: [hi | lo] halves
    __shared__ float sStage[64 * 17];  // h-tile staging (pad 17 vs bank conflicts)
    const int tid   = threadIdx.x;
    const int lane  = tid & 63;
    const int w     = tid >> 6;
    const int layer = blockIdx.x >> 6;
    const int n0    = (int)(blockIdx.x & 63) * 16;
    const int m0    = w * 16;
    const int rb    = lane & 15;
    const int q4    = lane >> 4;
    const int arow  = m0 + rb;
    const size_t BH = 65536;
    const int srow  = tid >> 2;           // store phase: row 0..63
    const int sc4   = (tid & 3) * 4;      // store phase: col group

    // ---- stage weight slice into LDS, XOR-swizzled on 16B quads ----
    if (layer == 0) {
        for (int i = 0; i < 16; ++i) {
            int s    = i * 256 + tid;
            int arr  = s >> 11;
            int r    = (s >> 7) & 15;
            int g    = s & 127;
            int slot = g ^ (r & 7);
            const u16* src = (arr ? Wh0l : Wh0h) + (size_t)(n0 + r) * 1024 + g * 8;
            *reinterpret_cast<int4*>(sW + arr * 16384 + r * 1024 + slot * 8) =
                *reinterpret_cast<const int4*>(src);
        }
    } else {
        for (int i = 0; i < 32; ++i) {
            int s    = i * 256 + tid;
            int arr  = s >> 12;
            int r    = (s >> 8) & 15;
            int g    = s & 255;
            int slot = g ^ (r & 7);
            const u16* src;
            if (g < 128) src = (arr ? Wx1l : Wx1h) + (size_t)(n0 + r) * 1024 + g * 8;
            else         src = (arr ? Wh1l : Wh1h) + (size_t)(n0 + r) * 1024 + (g - 128) * 8;
            *reinterpret_cast<int4*>(sW + arr * 32768 + r * 2048 + slot * 8) =
                *reinterpret_cast<const int4*>(src);
        }
    }
    __syncthreads();

    if (layer == 0) {
        for (int t = 0; t < 70; ++t) {
            if (t > 0) wait_count(flags + (t - 1), 64);
            const u16* hph = t ? H0h + (size_t)(t - 1) * BH : hs0h;
            const u16* hpl = t ? H0l + (size_t)(t - 1) * BH : hs0l;
            f32x4 acc = {0.f, 0.f, 0.f, 0.f};
            #pragma unroll 8
            for (int kt = 0; kt < 32; ++kt) {
                short8 ah = *reinterpret_cast<const short8*>(hph + (size_t)arow * 1024 + kt * 32 + q4 * 8);
                short8 al = *reinterpret_cast<const short8*>(hpl + (size_t)arow * 1024 + kt * 32 + q4 * 8);
                int slot = (kt * 4 + q4) ^ (rb & 7);
                short8 bh = *reinterpret_cast<const short8*>(sW + rb * 1024 + slot * 8);
                short8 bl = *reinterpret_cast<const short8*>(sW + 16384 + rb * 1024 + slot * 8);
                acc = MFMA_BF16(ah, bh, acc);
                acc = MFMA_BF16(ah, bl, acc);
                acc = MFMA_BF16(al, bh, acc);
            }
            #pragma unroll
            for (int r = 0; r < 4; ++r) {
                int m = m0 + q4 * 4 + r;
                size_t o = (size_t)t * BH + (size_t)m * 1024 + n0 + rb;
                sStage[m * 17 + rb] = tanhf(acc[r] + A0[o]);
            }
            __syncthreads();
            {
                float f0 = sStage[srow * 17 + sc4 + 0];
                float f1 = sStage[srow * 17 + sc4 + 1];
                float f2 = sStage[srow * 17 + sc4 + 2];
                float f3 = sStage[srow * 17 + sc4 + 3];
                u16 a,b,c,d, la,lb,lc,ld;
                split2(f0,a,la); split2(f1,b,lb); split2(f2,c,lc); split2(f3,d,ld);
                size_t o64 = ((size_t)t * BH + (size_t)srow * 1024 + n0 + sc4) >> 2;
                __hip_atomic_store((u64*)H0h + o64, pack4(a,b,c,d),
                                   __ATOMIC_RELAXED, __HIP_MEMORY_SCOPE_AGENT);
                __hip_atomic_store((u64*)H0l + o64, pack4(la,lb,lc,ld),
                                   __ATOMIC_RELAXED, __HIP_MEMORY_SCOPE_AGENT);
            }
            signal_done(flags + t);
        }
    } else {
        for (int t = 0; t < 70; ++t) {
            wait_count(flags + t, 64);
            if (t > 0) wait_count(flags + 70 + (t - 1), 64);
            const u16* h0h  = H0h + (size_t)t * BH;
            const u16* h0l  = H0l + (size_t)t * BH;
            const u16* h1ph = t ? H1h + (size_t)(t - 1) * BH : hs1h;
            const u16* h1pl = t ? H1l + (size_t)(t - 1) * BH : hs1l;
            f32x4 acc = {0.f, 0.f, 0.f, 0.f};
            #pragma unroll 8
            for (int kt = 0; kt < 32; ++kt) {
                short8 ah = *reinterpret_cast<const short8*>(h0h + (size_t)arow * 1024 + kt * 32 + q4 * 8);
                short8 al = *reinterpret_cast<const short8*>(h0l + (size_t)arow * 1024 + kt * 32 + q4 * 8);
                int slot = (kt * 4 + q4) ^ (rb & 7);
                short8 bh = *reinterpret_cast<const short8*>(sW + rb * 2048 + slot * 8);
                short8 bl = *reinterpret_cast<const short8*>(sW + 32768 + rb * 2048 + slot * 8);
                acc = MFMA_BF16(ah, bh, acc);
                acc = MFMA_BF16(ah, bl, acc);
                acc = MFMA_BF16(al, bh, acc);
            }
            #pragma unroll 8
            for (int kt = 32; kt < 64; ++kt) {
                int ko = (kt - 32) * 32;
                short8 ah = *reinterpret_cast<const short8*>(h1ph + (size_t)arow * 1024 + ko + q4 * 8);
                short8 al = *reinterpret_cast<const short8*>(h1pl + (size_t)arow * 1024 + ko + q4 * 8);
                int slot = (kt * 4 + q4) ^ (rb & 7);
                short8 bh = *reinterpret_cast<const short8*>(sW + rb * 2048 + slot * 8);
                short8 bl = *reinterpret_cast<const short8*>(sW + 32768 + rb * 2048 + slot * 8);
                acc = MFMA_BF16(ah, bh, acc);
                acc = MFMA_BF16(ah, bl, acc);
                acc = MFMA_BF16(al, bh, acc);
            }
            const int n = n0 + rb;
            #pragma unroll
            for (int r = 0; r < 4; ++r) {
                int m = m0 + q4 * 4 + r;
                sStage[m * 17 + rb] = tanhf(acc[r] + bh1[n]);
            }
            __syncthreads();
            {
                float f0 = sStage[srow * 17 + sc4 + 0];
                float f1 = sStage[srow * 17 + sc4 + 1];
                float f2 = sStage[srow * 17 + sc4 + 2];
                float f3 = sStage[srow * 17 + sc4 + 3];
                u16 a,b,c,d, la,lb,lc,ld;
                split2(f0,a,la); split2(f1,b,lb); split2(f2,c,lc); split2(f3,d,ld);
                size_t o64 = ((size_t)t * BH + (size_t)srow * 1024 + n0 + sc4) >> 2;
                __hip_atomic_store((u64*)H1h + o64, pack4(a,b,c,d),
                                   __ATOMIC_RELAXED, __HIP_MEMORY_SCOPE_AGENT);
                __hip_atomic_store((u64*)H1l + o64, pack4(la,lb,lc,ld),
                                   __ATOMIC_RELAXED, __HIP_MEMORY_SCOPE_AGENT);
            }
            signal_done(flags + 70 + t);
        }
    }
}

// ---------------- h_final tail (hi+lo reconstruction) ----------------------
__global__ __launch_bounds__(256) void hfinal_kernel(
    const u16* __restrict__ H0h, const u16* __restrict__ H0l,
    const u16* __restrict__ H1h, const u16* __restrict__ H1l,
    float* __restrict__ outp)
{
    int i = blockIdx.x * 256 + threadIdx.x;
    outp[i]         = bf16_f(H0h[i]) + bf16_f(H0l[i]);
    outp[65536 + i] = bf16_f(H1h[i]) + bf16_f(H1l[i]);
}

extern "C" void kernel_launch(void* const* d_in, const int* in_sizes, int n_in,
                              void* d_out, int out_size, void* d_ws, size_t ws_size,
                              hipStream_t stream)
{
    const int*   inputs = (const int*)  d_in[0];
    const float* hidden = (const float*)d_in[1];
    const float* embW   = (const float*)d_in[2];
    const float* Wx0    = (const float*)d_in[3];
    const float* Wx1    = (const float*)d_in[4];
    const float* Wh0    = (const float*)d_in[5];
    const float* bh0    = (const float*)d_in[6];
    const float* Wh1    = (const float*)d_in[7];
    const float* bh1    = (const float*)d_in[8];
    const float* Wy     = (const float*)d_in[9];
    const float* by     = (const float*)d_in[10];
    float* out = (float*)d_out;

    const int T = 70, B = 64, V = 10000, E = 512, H = 1024;
    const int M = T * B;
    const size_t MH = (size_t)M * H;
    const size_t BH = (size_t)B * H;

    char* wsb = (char*)d_ws;
    u16*   Wyh  = (u16*)(wsb);
    u16*   Wyl  = Wyh + (size_t)V * H;
    float* buf0 = (float*)(wsb + 40960000);
    u16*   H0h  = (u16*)(wsb + 59310080);
    u16*   H0l  = H0h + MH;
    u16*   H1h  = H0l + MH;
    u16*   H1l  = H1h + MH;
    u16*   Wx0h = H1l + MH;
    u16*   Wx0l = Wx0h + (size_t)H * E;
    u16*   Wx1h = Wx0l + (size_t)H * E;
    u16*   Wx1l = Wx1h + (size_t)H * H;
    u16*   Wh0h = Wx1l + (size_t)H * H;
    u16*   Wh0l = Wh0h + (size_t)H * H;
    u16*   Wh1h = Wh0l + (size_t)H * H;
    u16*   Wh1l = Wh1h + (size_t)H * H;
    u16*   hs0h = Wh1l + (size_t)H * H;
    u16*   hs0l = hs0h + BH;
    u16*   hs1h = hs0l + BH;
    u16*   hs1l = hs1h + BH;

    // d_out aliased scratch: gathered emb splits (dead after A0 GEMM) and
    // sync flags (dead after persist; overwritten by logits afterwards).
    u16*   Agh   = (u16*)((char*)d_out + 20971520);
    u16*   Agl   = Agh + (size_t)M * E;
    int*   flags = (int*)((char*)d_out + 104857600);   // +100 MB, 140 ints

    dim3 blk(256);

    hipMemsetAsync(flags, 0, 140 * sizeof(int), stream);

    // fused splits: all weights + both hidden layers in one launch.
    split_all_kernel<<<dim3(13713), blk, 0, stream>>>(
        Wx0, Wx0h, Wx0l,
        Wx1, Wx1h, Wx1l,
        Wh0, Wh0h, Wh0l,
        Wh1, Wh1h, Wh1l,
        Wy,  Wyh,  Wyl,
        hidden, hs0h, hs0l);   // hidden dst is contiguous: hs0h/hs0l then
                               // hs1h/hs1l follow in the ws layout
    gather_split_kernel<<<dim3((M*E)/1024), blk, 0, stream>>>(embW, inputs, Agh, Agl, (M*E)/4);

    // A0 = embsplit @ Wx0^T + bh0
    gemm_mfma<<<dim3(H/128, M/128), blk, 0, stream>>>(
        Agh, Agl, Wx0h, Wx0l, bh0, buf0, M, H, E);

    // persistent recurrence, flag-synced (R12 exact)
    {
        const float* A0p = buf0;
        void* args[] = {
            (void*)&A0p,
            (void*)&hs0h, (void*)&hs0l, (void*)&hs1h, (void*)&hs1l,
            (void*)&H0h,  (void*)&H0l,  (void*)&H1h,  (void*)&H1l,
            (void*)&Wh0h, (void*)&Wh0l, (void*)&Wx1h, (void*)&Wx1l,
            (void*)&Wh1h, (void*)&Wh1l, (void*)&bh1, (void*)&flags
        };
        hipLaunchCooperativeKernel(reinterpret_cast<void*>(rnn_persist2),
                                   dim3(128), blk, args, 0, stream);
    }

    hfinal_kernel<<<dim3(256), blk, 0, stream>>>(
        H0h + (size_t)(T-1) * BH, H0l + (size_t)(T-1) * BH,
        H1h + (size_t)(T-1) * BH, H1l + (size_t)(T-1) * BH,
        out + (size_t)M * V);

    // logits = H1split @ Wy^T + by   (XCD-aware bijective block remap)
    gemm_mfma_swz<<<dim3(35 * 79), blk, 0, stream>>>(
        H1h, H1l, Wyh, Wyl, by, out, M, V, H);
}